// Round 4
// baseline (70.282 us; speedup 1.0000x reference)
//
#include <hip/hip_runtime.h>
#include <math.h>

#define DHID   784
#define HID    1024
#define NB     10
#define MC_LD  800                         // padded leading dim for Mc rows
#define M2_OFF (11*MC_LD)                  // 8800
#define M2_LD  13
#define C0_OFF (M2_OFF + 64*M2_LD)         // 9632
#define WS_FLOATS 9648
#define DELTA0 7.0f

// ---------------------------------------------------------------------------
// ROUND 4 = ROUND 3 SOURCE, UNCHANGED, but each kernel launched TWICE.
// Marginal-cost probe: dur4 - dur3 = true (prep+main) duration if timing is
// kernel-bound; ~0 if the timed window is floored by harness overhead.
// Both kernels are idempotent so double-launch is correct & deterministic.
// ---------------------------------------------------------------------------

// prep: fold all weights.
// ws layout (floats):
//   [0 .. 8800)   Mc[11][800]: c<10 -> column c of M1 = W_in @ (g .* W_out)
//                              c==10 -> w_mean[d] = (1/1024) * sum_j W_in[d][j]
//   [8800..9632)  M2[64][13] : M2[h][c] = sum_j W_ph[h][j]*g[j]*W_out[j][c]
//   [9632..9642)  c0[10] = (b_in+b_ph)*g @ W_out + b_out
//   [9642]        bmean = mean(b_in)
// g[j] = 2 if j<5 else 1  (spiking gains provably constant: each top-k token
// spikes once and resets to 0, so V ends all-zero and top_k -> indices 0..4).
__global__ __launch_bounds__(256) void prep_kernel(
    const float* __restrict__ W_in,  const float* __restrict__ b_in,
    const float* __restrict__ W_ph,  const float* __restrict__ b_ph,
    const float* __restrict__ W_out, const float* __restrict__ b_out,
    float* __restrict__ ws) {
  __shared__ float wlds[HID * 11];           // 44 KB
  const int tid = threadIdx.x;

  for (int idx = tid; idx < HID * NB; idx += 256) {
    const int j = idx / NB;
    const int c = idx - j * NB;
    wlds[j * 11 + c] = W_out[idx];
  }
  __syncthreads();

  const int w = tid >> 6;
  const int l = tid & 63;
  const int b = blockIdx.x * 4 + w;          // 0..783 W_in; 784..847 W_ph; 848 bias
  if (b > DHID + 64) return;

  float acc[11];
#pragma unroll
  for (int c = 0; c < 11; ++c) acc[c] = 0.f;

#pragma unroll 4
  for (int it = 0; it < 16; ++it) {
    const int j = l + 64 * it;
    float wv, extra;
    if (b < DHID)           { wv = W_in[b * HID + j];          extra = wv;      }
    else if (b < DHID + 64) { wv = W_ph[(b - DHID) * HID + j]; extra = 0.f;     }
    else                    { wv = b_in[j] + b_ph[j];          extra = b_in[j]; }
    const float wg = (j < 5) ? 2.0f * wv : wv;
    const float* wr = &wlds[j * 11];
#pragma unroll
    for (int c = 0; c < 10; ++c) acc[c] += wg * wr[c];
    acc[10] += extra;
  }

#pragma unroll
  for (int c = 0; c < 11; ++c) {
    float v = acc[c];
    v += __shfl_xor(v, 1,  64);
    v += __shfl_xor(v, 2,  64);
    v += __shfl_xor(v, 4,  64);
    v += __shfl_xor(v, 8,  64);
    v += __shfl_xor(v, 16, 64);
    v += __shfl_xor(v, 32, 64);
    acc[c] = v;
  }

  if (l == 0) {
    if (b < DHID) {
#pragma unroll
      for (int c = 0; c < 10; ++c) ws[c * MC_LD + b] = acc[c];
      ws[10 * MC_LD + b] = acc[10] * (1.0f / HID);
    } else if (b < DHID + 64) {
      const int h = b - DHID;
#pragma unroll
      for (int c = 0; c < 10; ++c) ws[M2_OFF + h * M2_LD + c] = acc[c];
      ws[M2_OFF + h * M2_LD + 10] = 0.f;
      ws[M2_OFF + h * M2_LD + 11] = 0.f;
      ws[M2_OFF + h * M2_LD + 12] = 0.f;
    } else {
#pragma unroll
      for (int c = 0; c < 10; ++c) ws[C0_OFF + c] = acc[c] + b_out[c];
      ws[C0_OFF + 10] = acc[10] * (1.0f / HID);
    }
  }
}

// main: no LDS; Mc/M2/c0 (38 KB) via L1/L2. 1 row/lane, 16 rows/block,
// 1024 blocks -> 4 blocks/CU. ~80 VGPRs.
__global__ __launch_bounds__(256) void main_kernel(const float* __restrict__ x,
                                                   const float* __restrict__ ws,
                                                   float* __restrict__ out) {
  const int tid  = threadIdx.x;
  const int wav  = tid >> 6;
  const int lane = tid & 63;
  const int kl   = lane & 15;
  const int row  = blockIdx.x * 16 + wav * 4 + (lane >> 4);
  const float* x0 = x + (size_t)row * DHID;

  float acc[11];
#pragma unroll
  for (int c = 0; c < 11; ++c) acc[c] = 0.f;

#pragma unroll 2
  for (int i = 0; i < 12; ++i) {
    const int d = 4 * kl + 64 * i;
    const float4 xv = *(const float4*)(x0 + d);
#pragma unroll
    for (int c = 0; c < 11; ++c) {
      const float4 mv = *(const float4*)(ws + c * MC_LD + d);
      acc[c] += xv.x * mv.x + xv.y * mv.y + xv.z * mv.z + xv.w * mv.w;
    }
  }
  if (kl < 4) {                              // tail: d = 768 + 4*kl < 784
    const int d = 768 + 4 * kl;
    const float4 xv = *(const float4*)(x0 + d);
#pragma unroll
    for (int c = 0; c < 11; ++c) {
      const float4 mv = *(const float4*)(ws + c * MC_LD + d);
      acc[c] += xv.x * mv.x + xv.y * mv.y + xv.z * mv.z + xv.w * mv.w;
    }
  }

#pragma unroll
  for (int c = 0; c < 11; ++c) {
    float v = acc[c];
    v += __shfl_xor(v, 1, 64);
    v += __shfl_xor(v, 2, 64);
    v += __shfl_xor(v, 4, 64);
    v += __shfl_xor(v, 8, 64);
    acc[c] = v;
  }

  const float m    = acc[10] + ws[C0_OFF + 10];
  const float base = DELTA0 * m;
  float s1, c1, s2, c2;
  __sincosf((float)(kl + 1)  * base, &s1, &c1);
  __sincosf((float)(kl + 17) * base, &s2, &c2);
  const float* m2a = ws + M2_OFF + (kl)      * M2_LD;   // cos, h=kl
  const float* m2b = ws + M2_OFF + (kl + 16) * M2_LD;   // cos, h=kl+16
  const float* m2c = ws + M2_OFF + (kl + 32) * M2_LD;   // sin, h=kl+32
  const float* m2d = ws + M2_OFF + (kl + 48) * M2_LD;   // sin, h=kl+48
  float t[10];
#pragma unroll
  for (int c = 0; c < 10; ++c)
    t[c] = c1 * m2a[c] + c2 * m2b[c] + s1 * m2c[c] + s2 * m2d[c];
#pragma unroll
  for (int c = 0; c < 10; ++c) {
    float v = t[c];
    v += __shfl_xor(v, 1, 64);
    v += __shfl_xor(v, 2, 64);
    v += __shfl_xor(v, 4, 64);
    v += __shfl_xor(v, 8, 64);
    t[c] = v;
  }
  if (kl == 0) {
#pragma unroll
    for (int c = 0; c < 10; ++c)
      out[row * NB + c] = acc[c] + t[c] + ws[C0_OFF + c];
  }
}

// ---------------------------------------------------------------------------
extern "C" void kernel_launch(void* const* d_in, const int* in_sizes, int n_in,
                              void* d_out, int out_size, void* d_ws, size_t ws_size,
                              hipStream_t stream) {
  const float* x     = (const float*)d_in[0];
  const float* W_in  = (const float*)d_in[1];
  const float* b_in  = (const float*)d_in[2];
  const float* W_ph  = (const float*)d_in[3];
  const float* b_ph  = (const float*)d_in[4];
  const float* W_out = (const float*)d_in[5];
  const float* b_out = (const float*)d_in[6];
  float* out = (float*)d_out;
  float* ws  = (float*)d_ws;

  // Launch everything TWICE (idempotent): dur delta vs round 3 == true
  // kernel time (if kernel-bound) or ~0 (if externally floored).
  prep_kernel<<<(DHID + 64 + 1 + 3) / 4, 256, 0, stream>>>(W_in, b_in, W_ph, b_ph,
                                                           W_out, b_out, ws);
  main_kernel<<<1024, 256, 0, stream>>>(x, ws, out);
  prep_kernel<<<(DHID + 64 + 1 + 3) / 4, 256, 0, stream>>>(W_in, b_in, W_ph, b_ph,
                                                           W_out, b_out, ws);
  main_kernel<<<1024, 256, 0, stream>>>(x, ws, out);
}